// Round 1
// baseline (51.164 us; speedup 1.0000x reference)
//
#include <hip/hip_runtime.h>
#include <math.h>

// PathDDPM q_sample: x_t = sqrt(acp[t]) * x_0 + sqrt(1-acp[t]) * noise
// B=4096, L=2048, C=2. Outputs: (x_t, noise) concatenated flat, fp32.

#define TSTEPS 1000
#define BSTART 1e-4
#define BEND   0.02

// ---- Kernel 1: build sqrt(alphas_cumprod) and sqrt(1-alphas_cumprod) tables ----
// One wave (64 lanes). Lane l owns a 16-step chunk; serial local product in
// double, then a 6-step shuffle scan for the cross-lane prefix product.
__global__ void ddpm_schedule_kernel(float* __restrict__ ws) {
    const int lane = threadIdx.x;          // 0..63
    const int CHUNK = 16;                  // 64*16 = 1024 >= 1000
    const double step = (BEND - BSTART) / (double)(TSTEPS - 1);
    const int i0 = lane * CHUNK;

    // local product of (1 - beta_i) over this lane's chunk
    double p = 1.0;
    for (int k = 0; k < CHUNK; ++k) {
        int i = i0 + k;
        if (i < TSTEPS) {
            double beta = BSTART + step * (double)i;
            p *= (1.0 - beta);
        }
    }
    // inclusive scan of products across the 64-lane wave
    double scan = p;
    #pragma unroll
    for (int off = 1; off < 64; off <<= 1) {
        double o = __shfl_up(scan, off);
        if (lane >= off) scan *= o;
    }
    // exclusive prefix = previous lane's inclusive value
    double excl = __shfl_up(scan, 1);
    if (lane == 0) excl = 1.0;

    // walk chunk again, emitting sqrt tables
    double run = excl;
    for (int k = 0; k < CHUNK; ++k) {
        int i = i0 + k;
        if (i < TSTEPS) {
            double beta = BSTART + step * (double)i;
            run *= (1.0 - beta);
            ws[i]          = (float)sqrt(run);        // sqrt_alphas_cumprod
            ws[TSTEPS + i] = (float)sqrt(1.0 - run);  // sqrt_one_minus_alphas_cumprod
        }
    }
}

// ---- Kernel 2: fused q_sample + noise passthrough, float4-vectorized ----
__global__ void __launch_bounds__(256)
ddpm_qsample_kernel(const float4* __restrict__ x0,
                    const int*    __restrict__ t,
                    const float4* __restrict__ nz,
                    float4*       __restrict__ out_xt,
                    float4*       __restrict__ out_nz,
                    const float*  __restrict__ ws,
                    int n4) {
    const float* __restrict__ sa = ws;           // sqrt_alphas_cumprod
    const float* __restrict__ ss = ws + TSTEPS;  // sqrt_one_minus
    const int stride = gridDim.x * blockDim.x;
    for (int i = blockIdx.x * blockDim.x + threadIdx.x; i < n4; i += stride) {
        // row size L*C = 4096 floats = 1024 float4s -> b = i >> 10
        const int b  = i >> 10;
        const int tb = t[b];
        const float a = sa[tb];
        const float s = ss[tb];
        const float4 x = x0[i];
        const float4 n = nz[i];
        float4 o;
        o.x = fmaf(a, x.x, s * n.x);
        o.y = fmaf(a, x.y, s * n.y);
        o.z = fmaf(a, x.z, s * n.z);
        o.w = fmaf(a, x.w, s * n.w);
        out_xt[i] = o;
        out_nz[i] = n;
    }
}

extern "C" void kernel_launch(void* const* d_in, const int* in_sizes, int n_in,
                              void* d_out, int out_size, void* d_ws, size_t ws_size,
                              hipStream_t stream) {
    const float* x0 = (const float*)d_in[0];   // [B, L, 2] fp32
    const int*   t  = (const int*)  d_in[1];   // [B] int32
    const float* nz = (const float*)d_in[2];   // [B, L, 2] fp32
    float* out = (float*)d_out;                // [x_t | noise] concatenated
    float* ws  = (float*)d_ws;                 // 2*TSTEPS floats (8 KB)

    const int n  = 4096 * 2048 * 2;            // 16,777,216 elements per tensor
    const int n4 = n / 4;                      // 4,194,304 float4s

    ddpm_schedule_kernel<<<1, 64, 0, stream>>>(ws);
    ddpm_qsample_kernel<<<2048, 256, 0, stream>>>(
        (const float4*)x0, t, (const float4*)nz,
        (float4*)out, (float4*)(out + n), ws, n4);
}